// Round 2
// baseline (908.548 us; speedup 1.0000x reference)
//
#include <hip/hip_runtime.h>
#include <cstdint>
#include <cstddef>

constexpr int T_ = 128;
constexpr int S_ = 512;
constexpr int B_ = 256;
constexpr int START_ = T_ - 3;  // 125
constexpr int STOP_  = T_ - 2;  // 126
constexpr float NEGINF_ = -3.402823466e38f;

// Barrier that only drains LDS (lgkmcnt), NOT vmcnt: global ph-stores and
// e-prefetch loads legally stay in flight across it (thread-private data).
// __syncthreads() would emit s_waitcnt vmcnt(0) and stall ~200+ cyc/step.
__device__ __forceinline__ void lds_barrier() {
  asm volatile("s_waitcnt lgkmcnt(0)\n\ts_barrier" ::: "memory");
}

// ---------------------------------------------------------------------------
// Forward: value-only Viterbi recursion, stores part_hist (S,B,T) fp32.
// tid = 2j + h: thread pair (j,0),(j,1) are ADJACENT LANES of one wave, so
// the two half-range partial maxes combine via shfl_xor(1) — no LDS
// reduction stage. part[] is ping-ponged so ONE lgkm-only barrier per step
// suffices (step t reads buf[(t+1)&1], writes buf[t&1]).
// Bit-exact vs reference: fl monotone => max_i fl(fl(p+tr)+e)
//                                        == fl(max_i fl(p+tr) + e).
// ---------------------------------------------------------------------------
__global__ __launch_bounds__(256) void viterbi_forward(
    const float* __restrict__ feats,   // (B,S,T)
    const float* __restrict__ trans,   // (T,T)
    float* __restrict__ ph)            // (S,B,T) workspace
{
  const int b   = blockIdx.x;
  const int tid = threadIdx.x;
  const int j   = tid >> 1;            // 0..127
  const int h   = tid & 1;             // 0..1

  __shared__ alignas(16) float part[2][T_];

  // trans rows [h*64, h*64+64), column j -> registers (fixed over t)
  float tc[64];
  #pragma unroll
  for (int ii = 0; ii < 64; ++ii)
    tc[ii] = trans[(h * 64 + ii) * T_ + j];

  const float* fb = feats + (size_t)b * S_ * T_;

  float p0 = fb[j] + trans[START_ * T_ + j];
  if (h == 0) {
    part[0][j] = p0;
    ph[(size_t)b * T_ + j] = p0;
  }
  float e_next = fb[T_ + j];
  __syncthreads();

  for (int t = 1; t < S_; ++t) {
    float e_cur = e_next;
    if (t + 1 < S_) e_next = fb[(size_t)(t + 1) * T_ + j];

    const float4* p4 = (const float4*)part[(t - 1) & 1];
    float m0 = NEGINF_, m1 = NEGINF_, m2 = NEGINF_, m3 = NEGINF_;
    #pragma unroll
    for (int q = 0; q < 16; q += 4) {
      float4 a0 = p4[h * 16 + q + 0];
      float4 a1 = p4[h * 16 + q + 1];
      float4 a2 = p4[h * 16 + q + 2];
      float4 a3 = p4[h * 16 + q + 3];
      m0 = fmaxf(m0, fmaxf(fmaxf(a0.x + tc[4*q+ 0], a0.y + tc[4*q+ 1]),
                           fmaxf(a0.z + tc[4*q+ 2], a0.w + tc[4*q+ 3])));
      m1 = fmaxf(m1, fmaxf(fmaxf(a1.x + tc[4*q+ 4], a1.y + tc[4*q+ 5]),
                           fmaxf(a1.z + tc[4*q+ 6], a1.w + tc[4*q+ 7])));
      m2 = fmaxf(m2, fmaxf(fmaxf(a2.x + tc[4*q+ 8], a2.y + tc[4*q+ 9]),
                           fmaxf(a2.z + tc[4*q+10], a2.w + tc[4*q+11])));
      m3 = fmaxf(m3, fmaxf(fmaxf(a3.x + tc[4*q+12], a3.y + tc[4*q+13]),
                           fmaxf(a3.z + tc[4*q+14], a3.w + tc[4*q+15])));
    }
    float m = fmaxf(fmaxf(m0, m1), fmaxf(m2, m3));
    m = fmaxf(m, __shfl_xor(m, 1));    // combine the two i-halves (lane pair)
    float np = m + e_cur;
    if (h == 0) part[t & 1][j] = np;
    lds_barrier();
    if (h == 0) ph[((size_t)t * B_ + b) * T_ + j] = np;  // off critical path
  }
}

// ---------------------------------------------------------------------------
// Trace: 4 independent batch chains per wave (grid 64 x 64 threads) so the
// serial ptr -> LDS-gather -> ballot chains overlap. ph/feats rows are kept
// as a depth-4 rotating register pipeline per chain (row issued at iter k is
// consumed at iter k-3: ~3 iterations ≈ 900 cyc of slack, covers HBM miss).
// float2 packing: lane l holds elements {2l, 2l+1} of each row.
// bp recomputed on-path only, bit-exact incl. +e and first-occurrence argmax.
// ---------------------------------------------------------------------------
constexpr int NC_ = 4;   // chains per block
constexpr int D_  = 4;   // row pipeline depth
constexpr int TS_ = 130; // transT row stride (even: keeps float2 alignment)

__global__ __launch_bounds__(64) void viterbi_trace(
    const float* __restrict__ feats,   // (B,S,T)
    const void*  __restrict__ mask,    // (B,S) dtype detected at runtime
    const float* __restrict__ trans,   // (T,T)
    const float* __restrict__ ph,      // (S,B,T)
    int* __restrict__ out)             // (B,S) int32
{
  const int lane = threadIdx.x;
  const int b0   = blockIdx.x * NC_;

  __shared__ alignas(16) float transT[T_ * TS_];  // transT[j*TS + i] = trans[i][j]
  #pragma unroll 4
  for (int g = lane; g < T_ * T_; g += 64) {
    int i = g >> 7, jj = g & (T_ - 1);
    transT[jj * TS_ + i] = trans[g];
  }
  __syncthreads();

  const int w0 = *(const int*)mask;    // element (0,0) is always true

  int    lp[NC_], ptrc[NC_], pointer[NC_];
  float  tg[NC_], e[NC_];
  float2 P[NC_][D_], F[NC_][D_];

  #pragma unroll
  for (int c = 0; c < NC_; ++c) {
    const int b = b0 + c;
    // ---- sequence length (mask dtype: uint8 / float32 / int32) ----
    int len = 0;
    if (w0 == 0x01010101) {
      const unsigned char* m = (const unsigned char*)mask + (size_t)b * S_;
      for (int s = lane; s < S_; s += 64) len += (m[s] != 0);
    } else if (w0 == 0x3F800000) {
      const float* m = (const float*)mask + (size_t)b * S_;
      for (int s = lane; s < S_; s += 64) len += (m[s] != 0.0f);
    } else {
      const int* m = (const int*)mask + (size_t)b * S_;
      for (int s = lane; s < S_; s += 64) len += (m[s] != 0);
    }
    #pragma unroll
    for (int o = 32; o > 0; o >>= 1) len += __shfl_xor(len, o);
    lp[c] = len - 1;

    // ---- final pointer: first argmax_i(ph_lp[i] + trans[i][STOP]) ----
    float2 L = ((const float2*)(ph + ((size_t)lp[c] * B_ + b) * T_))[lane];
    float v0 = L.x + transT[STOP_ * TS_ + 2 * lane];
    float v1 = L.y + transT[STOP_ * TS_ + 2 * lane + 1];
    float mx = fmaxf(v0, v1);
    #pragma unroll
    for (int o = 32; o > 0; o >>= 1) mx = fmaxf(mx, __shfl_xor(mx, o));
    unsigned long long m0 = __ballot(v0 == mx);
    unsigned long long m1 = __ballot(v1 == mx);
    int p0 = m0 ? 2 * (__ffsll(m0) - 1)     : (1 << 30);
    int p1 = m1 ? 2 * (__ffsll(m1) - 1) + 1 : (1 << 30);
    int p  = min(p0, p1);
    pointer[c] = p;
    ptrc[c]    = p;
    if (lane == 0) out[b * S_ + (S_ - 1)] = p;

    // tg/e valid now only if lp == S-1; otherwise re-set at k == lp
    tg[c] = __shfl((p & 1) ? L.y : L.x, p >> 1);
    float2 FL = ((const float2*)(feats + ((size_t)b * S_ + lp[c]) * T_))[lane];
    e[c] = __shfl((p & 1) ? FL.y : FL.x, p >> 1);

    // ---- prime the row pipeline: P[d] = ph row (S-2-d), F[d] = feats row ----
    #pragma unroll
    for (int d = 0; d < D_; ++d) {
      int kr = S_ - 2 - d; if (kr < 0) kr = 0;
      P[c][d] = ((const float2*)(ph    + ((size_t)kr * B_ + b) * T_))[lane];
      F[c][d] = ((const float2*)(feats + ((size_t)b * S_ + kr) * T_))[lane];
    }
  }

  for (int k = S_ - 2; k >= 0; --k) {
    #pragma unroll
    for (int c = 0; c < NC_; ++c) {
      const int b = b0 + c;
      int val;
      if (k > lp[c]) {
        val = 0;                               // masked region: bp == 0
      } else if (k == lp[c]) {
        ptrc[c] = pointer[c];                  // overwritten bp row
        val = pointer[c];
      } else {
        // candidates c_i = fl(fl(ph_k[i] + trans[i,ptr]) + e), i = 2l, 2l+1
        const float* tr = transT + ptrc[c] * TS_ + 2 * lane;
        float cx = (P[c][0].x + tr[0]) + e[c];
        float cy = (P[c][0].y + tr[1]) + e[c];
        unsigned long long q0 = __ballot(cx == tg[c]);
        unsigned long long q1 = __ballot(cy == tg[c]);
        int a0 = q0 ? 2 * (__ffsll(q0) - 1)     : (1 << 30);
        int a1 = q1 ? 2 * (__ffsll(q1) - 1) + 1 : (1 << 30);
        ptrc[c] = min(a0, a1);
        val = ptrc[c];
      }
      if (lane == 0) out[b * S_ + k] = val;

      // extract next step's target/emission BEFORE rotating (P[0]=ph_k, F[0]=feats_k)
      int p = ptrc[c], pl = p >> 1;
      tg[c] = __shfl((p & 1) ? P[c][0].y : P[c][0].x, pl);
      e[c]  = __shfl((p & 1) ? F[c][0].y : F[c][0].x, pl);

      #pragma unroll
      for (int d = 0; d < D_ - 1; ++d) { P[c][d] = P[c][d + 1]; F[c][d] = F[c][d + 1]; }
      int kr = k - D_; if (kr < 0) kr = 0;     // clamped rows are never used
      P[c][D_ - 1] = ((const float2*)(ph    + ((size_t)kr * B_ + b) * T_))[lane];
      F[c][D_ - 1] = ((const float2*)(feats + ((size_t)b * S_ + kr) * T_))[lane];
    }
  }
}

extern "C" void kernel_launch(void* const* d_in, const int* in_sizes, int n_in,
                              void* d_out, int out_size, void* d_ws, size_t ws_size,
                              hipStream_t stream) {
  const float* feats = (const float*)d_in[0];   // (B,S,T) fp32
  const void*  mask  = d_in[1];                 // (B,S) bool-ish
  const float* trans = (const float*)d_in[2];   // (T,T) fp32
  float* ph = (float*)d_ws;                     // (S,B,T) fp32 = 64 MB
  int*   out = (int*)d_out;                     // (B,S) int32

  viterbi_forward<<<dim3(B_), dim3(256), 0, stream>>>(feats, trans, ph);
  viterbi_trace  <<<dim3(B_ / NC_), dim3(64), 0, stream>>>(feats, mask, trans, ph, out);
}

// Round 3
// 465.243 us; speedup vs baseline: 1.9528x; 1.9528x over previous
//
#include <hip/hip_runtime.h>
#include <cstdint>
#include <cstddef>

constexpr int T_ = 128;
constexpr int S_ = 512;
constexpr int B_ = 256;
constexpr int START_ = T_ - 3;  // 125
constexpr int STOP_  = T_ - 2;  // 126
constexpr float NEGINF_ = -3.402823466e38f;

// Barrier that only drains LDS (lgkmcnt), NOT vmcnt: global ph-stores and
// e-prefetch loads legally stay in flight across it (thread-private data).
__device__ __forceinline__ void lds_barrier() {
  asm volatile("s_waitcnt lgkmcnt(0)\n\ts_barrier" ::: "memory");
}

// readlane: wave-uniform lane index (SGPR) -> ~VALU-speed broadcast,
// vs __shfl which lowers to ds_bpermute (~LDS latency).
__device__ __forceinline__ float readlane_f(float v, int sl) {
  return __int_as_float(__builtin_amdgcn_readlane(__float_as_int(v), sl));
}

// ---------------------------------------------------------------------------
// Forward: value-only Viterbi recursion, stores part_hist (S,B,T) fp32.
// tid = 2j + h: the (j,0),(j,1) half-maxes combine via a DPP quad-perm pair
// swap (VALU speed) instead of ds_swizzle. part[] ping-ponged: one lgkm-only
// barrier per step. Bit-exact vs reference (fl monotone =>
// max_i fl(fl(p+tr)+e) == fl(max_i fl(p+tr) + e)).
// ---------------------------------------------------------------------------
__global__ __launch_bounds__(256) void viterbi_forward(
    const float* __restrict__ feats,   // (B,S,T)
    const float* __restrict__ trans,   // (T,T)
    float* __restrict__ ph)            // (S,B,T) workspace
{
  const int b   = blockIdx.x;
  const int tid = threadIdx.x;
  const int j   = tid >> 1;            // 0..127
  const int h   = tid & 1;             // 0..1

  __shared__ alignas(16) float part[2][T_];

  float tc[64];
  #pragma unroll
  for (int ii = 0; ii < 64; ++ii)
    tc[ii] = trans[(h * 64 + ii) * T_ + j];

  const float* fb = feats + (size_t)b * S_ * T_;

  float p0 = fb[j] + trans[START_ * T_ + j];
  if (h == 0) {
    part[0][j] = p0;
    ph[(size_t)b * T_ + j] = p0;
  }
  float e_next = fb[T_ + j];
  __syncthreads();

  for (int t = 1; t < S_; ++t) {
    float e_cur = e_next;
    if (t + 1 < S_) e_next = fb[(size_t)(t + 1) * T_ + j];

    const float4* p4 = (const float4*)part[(t - 1) & 1];
    float m0 = NEGINF_, m1 = NEGINF_, m2 = NEGINF_, m3 = NEGINF_;
    #pragma unroll
    for (int q = 0; q < 16; q += 4) {
      float4 a0 = p4[h * 16 + q + 0];
      float4 a1 = p4[h * 16 + q + 1];
      float4 a2 = p4[h * 16 + q + 2];
      float4 a3 = p4[h * 16 + q + 3];
      m0 = fmaxf(m0, fmaxf(fmaxf(a0.x + tc[4*q+ 0], a0.y + tc[4*q+ 1]),
                           fmaxf(a0.z + tc[4*q+ 2], a0.w + tc[4*q+ 3])));
      m1 = fmaxf(m1, fmaxf(fmaxf(a1.x + tc[4*q+ 4], a1.y + tc[4*q+ 5]),
                           fmaxf(a1.z + tc[4*q+ 6], a1.w + tc[4*q+ 7])));
      m2 = fmaxf(m2, fmaxf(fmaxf(a2.x + tc[4*q+ 8], a2.y + tc[4*q+ 9]),
                           fmaxf(a2.z + tc[4*q+10], a2.w + tc[4*q+11])));
      m3 = fmaxf(m3, fmaxf(fmaxf(a3.x + tc[4*q+12], a3.y + tc[4*q+13]),
                           fmaxf(a3.z + tc[4*q+14], a3.w + tc[4*q+15])));
    }
    float m = fmaxf(fmaxf(m0, m1), fmaxf(m2, m3));
    // pair swap (lanes 2k <-> 2k+1) via DPP quad_perm [1,0,3,2] = 0xB1
    int sw = __builtin_amdgcn_mov_dpp(__float_as_int(m), 0xB1, 0xF, 0xF, true);
    m = fmaxf(m, __int_as_float(sw));
    float np = m + e_cur;
    if (h == 0) part[t & 1][j] = np;
    lds_barrier();
    if (h == 0) ph[((size_t)t * B_ + b) * T_ + j] = np;  // off critical path
  }
}

// ---------------------------------------------------------------------------
// Trace: one wave (64 lanes) per b, grid 256. Masked tail [lp..S-2] is a
// parallel zero/pointer fill (no chase). Real chase runs k = lp-1 .. 0 with
// chunked A/B double-buffered row prefetch (distinct named buffers -> loads
// stay in flight a full 8-step process phase; no register rotation).
// Per-step serial chain: ds_read transT gather -> add/cmp -> ballot/ffs ->
// readlane (tg,e). Bit-exact first-occurrence argmax vs reference.
// ---------------------------------------------------------------------------
constexpr int CH_ = 8;   // chunk size (steps per buffer)
constexpr int TS_ = 130; // transT row stride (even: float2-aligned, 2-way ok)

__global__ __launch_bounds__(64) void viterbi_trace(
    const float* __restrict__ feats,   // (B,S,T)
    const void*  __restrict__ mask,    // (B,S) dtype detected at runtime
    const float* __restrict__ trans,   // (T,T)
    const float* __restrict__ ph,      // (S,B,T)
    int* __restrict__ out)             // (B,S) int32
{
  const int b    = blockIdx.x;
  const int lane = threadIdx.x;

  __shared__ alignas(16) float transT[T_ * TS_];  // transT[j*TS+i] = trans[i][j]
  #pragma unroll 4
  for (int g = lane; g < T_ * T_; g += 64) {
    int i = g >> 7, jj = g & (T_ - 1);
    transT[jj * TS_ + i] = trans[g];
  }
  __syncthreads();

  // ---- sequence length (mask dtype: uint8 / float32 / int32) ----
  int len = 0;
  {
    const int w0 = *(const int*)mask;  // element (0,0) is always true
    if (w0 == 0x01010101) {
      const unsigned char* m = (const unsigned char*)mask + (size_t)b * S_;
      for (int s = lane; s < S_; s += 64) len += (m[s] != 0);
    } else if (w0 == 0x3F800000) {
      const float* m = (const float*)mask + (size_t)b * S_;
      for (int s = lane; s < S_; s += 64) len += (m[s] != 0.0f);
    } else {
      const int* m = (const int*)mask + (size_t)b * S_;
      for (int s = lane; s < S_; s += 64) len += (m[s] != 0);
    }
    #pragma unroll
    for (int o = 32; o > 0; o >>= 1) len += __shfl_xor(len, o);
  }
  const int lp = len - 1;              // last valid position (>= S/2-1)

  // ---- final pointer: first argmax_i(ph_lp[i] + trans[i][STOP]) ----
  const float2 L = *(const float2*)(ph + ((size_t)lp * B_ + b) * T_ + 2 * lane);
  float v0 = L.x + transT[STOP_ * TS_ + 2 * lane];
  float v1 = L.y + transT[STOP_ * TS_ + 2 * lane + 1];
  float mx = fmaxf(v0, v1);
  #pragma unroll
  for (int o = 32; o > 0; o >>= 1) mx = fmaxf(mx, __shfl_xor(mx, o));
  {
    unsigned long long g0 = __ballot(v0 == mx);
    unsigned long long g1 = __ballot(v1 == mx);
    int p0 = g0 ? 2 * (__ffsll(g0) - 1)     : (1 << 30);
    int p1 = g1 ? 2 * (__ffsll(g1) - 1) + 1 : (1 << 30);
    int pointer = min(p0, p1);

    // ---- masked tail: out[k]=0 for lp<k<S-1; out[S-1]=out[lp]=pointer ----
    for (int k = lp + 1 + lane; k <= S_ - 2; k += 64) out[b * S_ + k] = 0;
    if (lane == 0) {
      out[b * S_ + (S_ - 1)] = pointer;
      if (lp < S_ - 1) out[b * S_ + lp] = pointer;
    }

    // ---- chase k = lp-1 .. 0 ----
    int   ptr = pointer;
    float tg  = readlane_f((ptr & 1) ? L.y : L.x, ptr >> 1);  // ph[lp][ptr]
    const float* fb = feats + (size_t)b * S_ * T_;
    const float2 FL = *(const float2*)(fb + (size_t)lp * T_ + 2 * lane);
    float e = readlane_f((ptr & 1) ? FL.y : FL.x, ptr >> 1);  // feats[lp][ptr]

    float2 PA[CH_], FA[CH_], PB[CH_], FB[CH_];

    auto issue = [&](float2 (&P)[CH_], float2 (&F)[CH_], int k0) {
      #pragma unroll
      for (int s = 0; s < CH_; ++s) {
        int k = k0 - s; if (k < 0) k = 0;     // clamped slots never used
        P[s] = *(const float2*)(ph + ((size_t)k * B_ + b) * T_ + 2 * lane);
        F[s] = *(const float2*)(fb + (size_t)k * T_ + 2 * lane);
      }
    };
    auto process = [&](const float2 (&P)[CH_], const float2 (&F)[CH_], int k0) {
      #pragma unroll
      for (int s = 0; s < CH_; ++s) {
        const int k = k0 - s;
        if (k >= 0) {
          // candidates c_i = fl(fl(ph_k[i]+trans[i,ptr]) + e), i = 2l, 2l+1
          const float2 tr = *(const float2*)(transT + ptr * TS_ + 2 * lane);
          float cx = (P[s].x + tr.x) + e;
          float cy = (P[s].y + tr.y) + e;
          unsigned long long q0 = __ballot(cx == tg);
          unsigned long long q1 = __ballot(cy == tg);
          int a0 = q0 ? 2 * (__ffsll(q0) - 1)     : (1 << 30);
          int a1 = q1 ? 2 * (__ffsll(q1) - 1) + 1 : (1 << 30);
          ptr = min(a0, a1);
          if (lane == 0) out[b * S_ + k] = ptr;
          // next step (k-1) targets ph_k[ptr], feats[k][ptr]
          tg = readlane_f((ptr & 1) ? P[s].y : P[s].x, ptr >> 1);
          e  = readlane_f((ptr & 1) ? F[s].y : F[s].x, ptr >> 1);
        }
      }
    };

    issue(PA, FA, lp - 1);
    for (int k0 = lp - 1; k0 >= 0; k0 -= 2 * CH_) {
      issue(PB, FB, k0 - CH_);
      process(PA, FA, k0);
      issue(PA, FA, k0 - 2 * CH_);
      process(PB, FB, k0 - CH_);
    }
  }
}

extern "C" void kernel_launch(void* const* d_in, const int* in_sizes, int n_in,
                              void* d_out, int out_size, void* d_ws, size_t ws_size,
                              hipStream_t stream) {
  const float* feats = (const float*)d_in[0];   // (B,S,T) fp32
  const void*  mask  = d_in[1];                 // (B,S) bool-ish
  const float* trans = (const float*)d_in[2];   // (T,T) fp32
  float* ph = (float*)d_ws;                     // (S,B,T) fp32 = 64 MB
  int*   out = (int*)d_out;                     // (B,S) int32

  viterbi_forward<<<dim3(B_), dim3(256), 0, stream>>>(feats, trans, ph);
  viterbi_trace  <<<dim3(B_), dim3(64), 0, stream>>>(feats, mask, trans, ph, out);
}

// Round 4
// 455.368 us; speedup vs baseline: 1.9952x; 1.0217x over previous
//
#include <hip/hip_runtime.h>
#include <cstdint>
#include <cstddef>

constexpr int T_ = 128;
constexpr int S_ = 512;
constexpr int B_ = 256;
constexpr int START_ = T_ - 3;  // 125
constexpr int STOP_  = T_ - 2;  // 126
constexpr float NEGINF_ = -3.402823466e38f;

// Barrier that only drains LDS (lgkmcnt), NOT vmcnt: global ph-stores and
// e-prefetch loads legally stay in flight across it (thread-private data).
__device__ __forceinline__ void lds_barrier() {
  asm volatile("s_waitcnt lgkmcnt(0)\n\ts_barrier" ::: "memory");
}

// readlane: wave-uniform lane index (SGPR) -> ~VALU-speed broadcast,
// vs __shfl which lowers to ds_bpermute (~LDS latency).
__device__ __forceinline__ float readlane_f(float v, int sl) {
  return __int_as_float(__builtin_amdgcn_readlane(__float_as_int(v), sl));
}

// max-reduce over the 8 ig-lanes (lane bits [0,3)) entirely in DPP:
// quad xor1 (0xB1), quad xor2 (0x4E), half-row mirror (0x141 == lane^7,
// valid because the value is quad-uniform after the first two stages).
__device__ __forceinline__ float ig_reduce_max(float m) {
  int x = __builtin_amdgcn_mov_dpp(__float_as_int(m), 0xB1, 0xF, 0xF, true);
  m = fmaxf(m, __int_as_float(x));
  x = __builtin_amdgcn_mov_dpp(__float_as_int(m), 0x4E, 0xF, 0xF, true);
  m = fmaxf(m, __int_as_float(x));
  x = __builtin_amdgcn_mov_dpp(__float_as_int(m), 0x141, 0xF, 0xF, true);
  m = fmaxf(m, __int_as_float(x));
  return m;
}

// ---------------------------------------------------------------------------
// Forward: value-only Viterbi recursion, stores part_hist (S,B,T) fp32.
// Tiling: thread (ig, jg) covers i in [16ig,16ig+16) x j in [4jg,4jg+4):
//   - part chunk ig: 4 ds_read_b128 per thread -> 16 wave-instrs/CU/step
//     (was 64), conflict-free via +4-float pad per 16-float chunk
//     (float4-index 5*ig+q spans all 8 bank groups; 8-lane broadcast each).
//   - trans tile in 64 VGPRs (fixed over t).
//   - cross-ig max reduction in DPP (VALU speed), +e folded after.
// One lgkm-only barrier/step, ping-pong part buffers.
// Bit-exact vs reference: max is exactly associative/commutative, and
// fl monotone => max_i fl(fl(p+tr)+e) == fl(max_i fl(p+tr) + e).
// ---------------------------------------------------------------------------
__global__ __launch_bounds__(256) void viterbi_forward(
    const float* __restrict__ feats,   // (B,S,T)
    const float* __restrict__ trans,   // (T,T)
    float* __restrict__ ph)            // (S,B,T) workspace
{
  const int tid  = threadIdx.x;
  const int lane = tid & 63;
  const int w    = tid >> 6;           // wave 0..3
  const int ig   = lane & 7;           // i-chunk
  const int jl   = lane >> 3;          // 0..7
  const int jg   = w * 8 + jl;         // 0..31
  const int j0   = jg * 4;
  const int b    = blockIdx.x;

  // padded part: value i lives at float offset i + 4*(i>>4); 160 floats/buf
  __shared__ alignas(16) float part[2][160];

  // trans tile: rows 16ig..16ig+15, cols j0..j0+3 (float4 per row)
  float4 tc[16];
  #pragma unroll
  for (int ii = 0; ii < 16; ++ii)
    tc[ii] = *(const float4*)&trans[(16 * ig + ii) * T_ + j0];

  const float* fb = feats + (size_t)b * S_ * T_;
  const int woff = j0 + 4 * (jg >> 2);   // padded write offset for j-quad

  // t = 0: part0 = emit[0] + trans[START,:]
  float4 e0 = *(const float4*)&fb[j0];
  float4 ts = *(const float4*)&trans[START_ * T_ + j0];
  float4 p0 = make_float4(e0.x + ts.x, e0.y + ts.y, e0.z + ts.z, e0.w + ts.w);
  if (ig == 0) {
    *(float4*)&part[0][woff] = p0;
    *(float4*)&ph[(size_t)b * T_ + j0] = p0;
  }
  float4 e_next = *(const float4*)&fb[T_ + j0];
  __syncthreads();

  for (int t = 1; t < S_; ++t) {
    float4 e_cur = e_next;
    if (t + 1 < S_) e_next = *(const float4*)&fb[(size_t)(t + 1) * T_ + j0];

    const float4* p4 = (const float4*)part[(t - 1) & 1];
    float4 p[4];
    #pragma unroll
    for (int q = 0; q < 4; ++q) p[q] = p4[5 * ig + q];

    float m0 = NEGINF_, m1 = NEGINF_, m2 = NEGINF_, m3 = NEGINF_;
    #pragma unroll
    for (int q = 0; q < 4; ++q) {
      float4 pv = p[q];
      float4 t0 = tc[4 * q + 0], t1 = tc[4 * q + 1];
      float4 t2 = tc[4 * q + 2], t3 = tc[4 * q + 3];
      m0 = fmaxf(m0, fmaxf(fmaxf(pv.x + t0.x, pv.y + t1.x),
                           fmaxf(pv.z + t2.x, pv.w + t3.x)));
      m1 = fmaxf(m1, fmaxf(fmaxf(pv.x + t0.y, pv.y + t1.y),
                           fmaxf(pv.z + t2.y, pv.w + t3.y)));
      m2 = fmaxf(m2, fmaxf(fmaxf(pv.x + t0.z, pv.y + t1.z),
                           fmaxf(pv.z + t2.z, pv.w + t3.z)));
      m3 = fmaxf(m3, fmaxf(fmaxf(pv.x + t0.w, pv.y + t1.w),
                           fmaxf(pv.z + t2.w, pv.w + t3.w)));
    }
    float4 np4 = make_float4(ig_reduce_max(m0) + e_cur.x,
                             ig_reduce_max(m1) + e_cur.y,
                             ig_reduce_max(m2) + e_cur.z,
                             ig_reduce_max(m3) + e_cur.w);
    if (ig == 0) *(float4*)&part[t & 1][woff] = np4;
    lds_barrier();
    if (ig == 0)
      *(float4*)&ph[((size_t)t * B_ + b) * T_ + j0] = np4;  // off critical path
  }
}

// ---------------------------------------------------------------------------
// Trace: one wave (64 lanes) per b, grid 256. Masked tail [lp..S-2] is a
// parallel zero/pointer fill (no chase). Real chase runs k = lp-1 .. 0 with
// chunked A/B double-buffered row prefetch (distinct named buffers -> loads
// stay in flight a full 8-step process phase; no register rotation).
// Per-step serial chain: ds_read transT gather -> add/cmp -> ballot/ffs ->
// readlane (tg,e). Bit-exact first-occurrence argmax vs reference.
// ---------------------------------------------------------------------------
constexpr int CH_ = 8;   // chunk size (steps per buffer)
constexpr int TS_ = 130; // transT row stride (even: float2-aligned, 2-way ok)

__global__ __launch_bounds__(64) void viterbi_trace(
    const float* __restrict__ feats,   // (B,S,T)
    const void*  __restrict__ mask,    // (B,S) dtype detected at runtime
    const float* __restrict__ trans,   // (T,T)
    const float* __restrict__ ph,      // (S,B,T)
    int* __restrict__ out)             // (B,S) int32
{
  const int b    = blockIdx.x;
  const int lane = threadIdx.x;

  __shared__ alignas(16) float transT[T_ * TS_];  // transT[j*TS+i] = trans[i][j]
  #pragma unroll 4
  for (int g = lane; g < T_ * T_; g += 64) {
    int i = g >> 7, jj = g & (T_ - 1);
    transT[jj * TS_ + i] = trans[g];
  }
  __syncthreads();

  // ---- sequence length (mask dtype: uint8 / float32 / int32) ----
  int len = 0;
  {
    const int w0 = *(const int*)mask;  // element (0,0) is always true
    if (w0 == 0x01010101) {
      const unsigned char* m = (const unsigned char*)mask + (size_t)b * S_;
      for (int s = lane; s < S_; s += 64) len += (m[s] != 0);
    } else if (w0 == 0x3F800000) {
      const float* m = (const float*)mask + (size_t)b * S_;
      for (int s = lane; s < S_; s += 64) len += (m[s] != 0.0f);
    } else {
      const int* m = (const int*)mask + (size_t)b * S_;
      for (int s = lane; s < S_; s += 64) len += (m[s] != 0);
    }
    #pragma unroll
    for (int o = 32; o > 0; o >>= 1) len += __shfl_xor(len, o);
  }
  const int lp = len - 1;              // last valid position (>= S/2-1)

  // ---- final pointer: first argmax_i(ph_lp[i] + trans[i][STOP]) ----
  const float2 L = *(const float2*)(ph + ((size_t)lp * B_ + b) * T_ + 2 * lane);
  float v0 = L.x + transT[STOP_ * TS_ + 2 * lane];
  float v1 = L.y + transT[STOP_ * TS_ + 2 * lane + 1];
  float mx = fmaxf(v0, v1);
  #pragma unroll
  for (int o = 32; o > 0; o >>= 1) mx = fmaxf(mx, __shfl_xor(mx, o));
  {
    unsigned long long g0 = __ballot(v0 == mx);
    unsigned long long g1 = __ballot(v1 == mx);
    int p0 = g0 ? 2 * (__ffsll(g0) - 1)     : (1 << 30);
    int p1 = g1 ? 2 * (__ffsll(g1) - 1) + 1 : (1 << 30);
    int pointer = min(p0, p1);

    // ---- masked tail: out[k]=0 for lp<k<S-1; out[S-1]=out[lp]=pointer ----
    for (int k = lp + 1 + lane; k <= S_ - 2; k += 64) out[b * S_ + k] = 0;
    if (lane == 0) {
      out[b * S_ + (S_ - 1)] = pointer;
      if (lp < S_ - 1) out[b * S_ + lp] = pointer;
    }

    // ---- chase k = lp-1 .. 0 ----
    int   ptr = pointer;
    float tg  = readlane_f((ptr & 1) ? L.y : L.x, ptr >> 1);  // ph[lp][ptr]
    const float* fb = feats + (size_t)b * S_ * T_;
    const float2 FL = *(const float2*)(fb + (size_t)lp * T_ + 2 * lane);
    float e = readlane_f((ptr & 1) ? FL.y : FL.x, ptr >> 1);  // feats[lp][ptr]

    float2 PA[CH_], FA[CH_], PB[CH_], FB[CH_];

    auto issue = [&](float2 (&P)[CH_], float2 (&F)[CH_], int k0) {
      #pragma unroll
      for (int s = 0; s < CH_; ++s) {
        int k = k0 - s; if (k < 0) k = 0;     // clamped slots never used
        P[s] = *(const float2*)(ph + ((size_t)k * B_ + b) * T_ + 2 * lane);
        F[s] = *(const float2*)(fb + (size_t)k * T_ + 2 * lane);
      }
    };
    auto process = [&](const float2 (&P)[CH_], const float2 (&F)[CH_], int k0) {
      #pragma unroll
      for (int s = 0; s < CH_; ++s) {
        const int k = k0 - s;
        if (k >= 0) {
          // candidates c_i = fl(fl(ph_k[i]+trans[i,ptr]) + e), i = 2l, 2l+1
          const float2 tr = *(const float2*)(transT + ptr * TS_ + 2 * lane);
          float cx = (P[s].x + tr.x) + e;
          float cy = (P[s].y + tr.y) + e;
          unsigned long long q0 = __ballot(cx == tg);
          unsigned long long q1 = __ballot(cy == tg);
          int a0 = q0 ? 2 * (__ffsll(q0) - 1)     : (1 << 30);
          int a1 = q1 ? 2 * (__ffsll(q1) - 1) + 1 : (1 << 30);
          ptr = min(a0, a1);
          if (lane == 0) out[b * S_ + k] = ptr;
          // next step (k-1) targets ph_k[ptr], feats[k][ptr]
          tg = readlane_f((ptr & 1) ? P[s].y : P[s].x, ptr >> 1);
          e  = readlane_f((ptr & 1) ? F[s].y : F[s].x, ptr >> 1);
        }
      }
    };

    issue(PA, FA, lp - 1);
    for (int k0 = lp - 1; k0 >= 0; k0 -= 2 * CH_) {
      issue(PB, FB, k0 - CH_);
      process(PA, FA, k0);
      issue(PA, FA, k0 - 2 * CH_);
      process(PB, FB, k0 - CH_);
    }
  }
}

extern "C" void kernel_launch(void* const* d_in, const int* in_sizes, int n_in,
                              void* d_out, int out_size, void* d_ws, size_t ws_size,
                              hipStream_t stream) {
  const float* feats = (const float*)d_in[0];   // (B,S,T) fp32
  const void*  mask  = d_in[1];                 // (B,S) bool-ish
  const float* trans = (const float*)d_in[2];   // (T,T) fp32
  float* ph = (float*)d_ws;                     // (S,B,T) fp32 = 64 MB
  int*   out = (int*)d_out;                     // (B,S) int32

  viterbi_forward<<<dim3(B_), dim3(256), 0, stream>>>(feats, trans, ph);
  viterbi_trace  <<<dim3(B_), dim3(64), 0, stream>>>(feats, mask, trans, ph, out);
}